// Round 1
// baseline (254.544 us; speedup 1.0000x reference)
//
#include <hip/hip_runtime.h>

#define BB 8
#define CC 8
#define HH 512
#define WW 512
#define HWSZ (HH * WW)

__device__ __forceinline__ float fast_sigmoid(float x) {
    // 1 / (1 + exp(-x)); rcp approx (~1 ulp) is far within the 0.0875 threshold
    float e = __expf(-x);
    return __builtin_amdgcn_rcpf(1.0f + e);
}

// BCE element for binary t in {0,1}: -(t*max(log p,-100) + (1-t)*max(log(1-p),-100))
// With binary t this is exactly -max(log(sel), -100) where sel = t ? p : 1-p.
__device__ __forceinline__ float bce_elem(float p, float t) {
    float sel = (t > 0.5f) ? p : (1.0f - p);
    float lg = __logf(sel);          // log(0) = -inf -> clamped to -100
    return -fmaxf(lg, -100.0f);
}

__device__ __forceinline__ void branch_eval(
    const float* __restrict__ X, int b, int h, int w,
    int hm, int hp, int wm, int wp,
    float mh0, float mh1, float mw0, float mw1,
    const float* conv,
    float& glo, float& vmin, float& bicon, float& conn)
{
    const float* base = X + b * CC * HWSZ;
    const int rc = h * WW + w;   // center
    const int rm = hm * WW;      // row above (clamped)
    const int rp = hp * WW;      // row below (clamped)

    float s[8];
#pragma unroll
    for (int c = 0; c < 8; ++c)
        s[c] = fast_sigmoid(base[c * HWSZ + rc]);

    // neighbor for vote k uses channel (7-k); masks zero out out-of-range shifts
    float n[8];
    n[0] = fast_sigmoid(base[7 * HWSZ + rm + wm]) * (mh0 * mw0); // c7[h-1,w-1]
    n[1] = fast_sigmoid(base[6 * HWSZ + rm + w ]) *  mh0;        // c6[h-1,w  ]
    n[2] = fast_sigmoid(base[5 * HWSZ + rm + wp]) * (mh0 * mw1); // c5[h-1,w+1]
    n[3] = fast_sigmoid(base[4 * HWSZ + h * WW + wm]) * mw0;     // c4[h,  w-1]
    n[4] = fast_sigmoid(base[3 * HWSZ + h * WW + wp]) * mw1;     // c3[h,  w+1]
    n[5] = fast_sigmoid(base[2 * HWSZ + rp + wm]) * (mh1 * mw0); // c2[h+1,w-1]
    n[6] = fast_sigmoid(base[1 * HWSZ + rp + w ]) *  mh1;        // c1[h+1,w  ]
    n[7] = fast_sigmoid(base[0 * HWSZ + rp + wp]) * (mh1 * mw1); // c0[h+1,w+1]

    float vsum = 0.0f;
    vmin = 1e30f;
    bicon = 0.0f;
    conn = 0.0f;
#pragma unroll
    for (int k = 0; k < 8; ++k) {
        float v = s[k] * n[k];
        vsum += v;
        vmin = fminf(vmin, v);
        bicon += bce_elem(v, conv[k]);
        conn  += bce_elem(s[k], conv[k]);
    }
    glo = vsum * 0.125f;
}

__global__ __launch_bounds__(256) void bicon_loss_kernel(
    const float* __restrict__ atts, const float* __restrict__ dets,
    const float* __restrict__ target, const float* __restrict__ con,
    float* __restrict__ out)
{
    const int idx = blockIdx.x * 256 + threadIdx.x;   // pixel id in [0, B*H*W)
    const int w   = idx & (WW - 1);
    const int row = idx >> 9;        // b*H + h
    const int h   = row & (HH - 1);
    const int b   = row >> 9;

    // clamped neighbor coords + validity masks (branchless OOB handling)
    const int   hm  = (h > 0)      ? h - 1 : 0;
    const int   hp  = (h < HH - 1) ? h + 1 : HH - 1;
    const int   wm  = (w > 0)      ? w - 1 : 0;
    const int   wp  = (w < WW - 1) ? w + 1 : WW - 1;
    const float mh0 = (h > 0)      ? 1.0f : 0.0f;
    const float mh1 = (h < HH - 1) ? 1.0f : 0.0f;
    const float mw0 = (w > 0)      ? 1.0f : 0.0f;
    const float mw1 = (w < WW - 1) ? 1.0f : 0.0f;

    // con_target channels + edge mask
    const int rc = h * WW + w;
    float conv[8];
    float csum = 0.0f;
#pragma unroll
    for (int c = 0; c < 8; ++c) {
        conv[c] = con[b * CC * HWSZ + c * HWSZ + rc];
        csum += conv[c];
    }
    const float edge = (csum < 8.0f && csum > 0.0f) ? 1.0f : 0.0f;
    const float t = target[b * HWSZ + rc];

    float glo1, vmin1, bi1, co1;
    float glo2, vmin2, bi2, co2;
    branch_eval(atts, b, h, w, hm, hp, wm, wp, mh0, mh1, mw0, mw1, conv,
                glo1, vmin1, bi1, co1);
    branch_eval(dets, b, h, w, hm, hp, wm, wp, mh0, mh1, mw0, mw1, conv,
                glo2, vmin2, bi2, co2);

    const float dec = glo2 * (1.0f - edge) + (1.0f - vmin2) * edge;

    const float wbic = 0.2f / (float)(BB * CC * HWSZ);
    const float wcon = 0.8f / (float)(BB * CC * HWSZ);
    const float wpix = 1.0f / (float)(BB * HWSZ);

    float local = wbic * (bi1 + bi2)
                + wcon * (co1 + co2)
                + wpix * (bce_elem(glo1, t) + bce_elem(dec, t));

    // wave-64 butterfly reduce, then one atomic per block
#pragma unroll
    for (int off = 32; off > 0; off >>= 1)
        local += __shfl_down(local, off, 64);

    __shared__ float wsum[4];
    const int lane = threadIdx.x & 63;
    const int wid  = threadIdx.x >> 6;
    if (lane == 0) wsum[wid] = local;
    __syncthreads();
    if (threadIdx.x == 0) {
        float s = wsum[0] + wsum[1] + wsum[2] + wsum[3];
        atomicAdd(out, s);
    }
}

extern "C" void kernel_launch(void* const* d_in, const int* in_sizes, int n_in,
                              void* d_out, int out_size, void* d_ws, size_t ws_size,
                              hipStream_t stream) {
    const float* atts   = (const float*)d_in[0];
    const float* dets   = (const float*)d_in[1];
    const float* target = (const float*)d_in[2];
    const float* con    = (const float*)d_in[3];
    float* out = (float*)d_out;

    // d_out is poisoned before every launch — zero it on-stream (capture-safe)
    hipMemsetAsync(out, 0, sizeof(float), stream);

    const int npix = BB * HH * WW;               // 2,097,152
    bicon_loss_kernel<<<npix / 256, 256, 0, stream>>>(atts, dets, target, con, out);
}

// Round 2
// 201.381 us; speedup vs baseline: 1.2640x; 1.2640x over previous
//
#include <hip/hip_runtime.h>

#define BB 8
#define CC 8
#define HH 512
#define WW 512
#define HWSZ (HH * WW)

typedef float v4 __attribute__((ext_vector_type(4)));

// unaligned (4B-aligned) 16B load
__device__ __forceinline__ v4 uload4(const float* __restrict__ p) {
    v4 r;
    __builtin_memcpy(&r, p, sizeof(v4));
    return r;
}
// 16B-aligned load
__device__ __forceinline__ v4 aload4(const float* __restrict__ p) {
    return *(const v4* __restrict__)p;
}

__device__ __forceinline__ v4 sig4(v4 x) {
    v4 r;
#pragma unroll
    for (int i = 0; i < 4; ++i)
        r[i] = __builtin_amdgcn_rcpf(1.0f + __expf(-x[i]));
    return r;
}

// BCE term in log2 space (multiply total by ln2 at the end).
// ref clamp: max(log p, -100)  ->  max(log2 p, -100/ln2)
__device__ __forceinline__ float bce2(float p, float t) {
    float sel = (t > 0.5f) ? p : (1.0f - p);
    return -fmaxf(__log2f(sel), -144.26950409f);
}

__device__ __forceinline__ void branch_eval(
    const float* __restrict__ base,     // X + b*CC*HWSZ
    int offC, int offU, int offD,       // h*W+w0, hm*W+w0, hp*W+w0
    float mh0, float mh1, v4 mwL, v4 mwR,
    const v4* __restrict__ conv4,
    v4& glo, v4& vmin, float& bicon, float& conn)
{
    v4 s[8];
#pragma unroll
    for (int c = 0; c < 8; ++c)
        s[c] = sig4(aload4(base + c * HWSZ + offC));

    v4 n[8];
    n[0] = sig4(uload4(base + 7 * HWSZ + offU - 1)) * (mh0 * mwL);
    n[1] = sig4(aload4(base + 6 * HWSZ + offU    )) *  mh0;
    n[2] = sig4(uload4(base + 5 * HWSZ + offU + 1)) * (mh0 * mwR);
    n[3] = sig4(uload4(base + 4 * HWSZ + offC - 1)) *  mwL;
    n[4] = sig4(uload4(base + 3 * HWSZ + offC + 1)) *  mwR;
    n[5] = sig4(uload4(base + 2 * HWSZ + offD - 1)) * (mh1 * mwL);
    n[6] = sig4(aload4(base + 1 * HWSZ + offD    )) *  mh1;
    n[7] = sig4(uload4(base + 0 * HWSZ + offD + 1)) * (mh1 * mwR);

    v4 vsum = {0.0f, 0.0f, 0.0f, 0.0f};
    vmin = {1e30f, 1e30f, 1e30f, 1e30f};
    bicon = 0.0f;
    conn = 0.0f;
#pragma unroll
    for (int k = 0; k < 8; ++k) {
        v4 v = s[k] * n[k];
        vsum += v;
        vmin = __builtin_elementwise_min(vmin, v);
#pragma unroll
        for (int i = 0; i < 4; ++i) {
            bicon += bce2(v[i],    conv4[k][i]);
            conn  += bce2(s[k][i], conv4[k][i]);
        }
    }
    glo = vsum * 0.125f;
}

__global__ __launch_bounds__(256) void bicon_loss_kernel(
    const float* __restrict__ atts, const float* __restrict__ dets,
    const float* __restrict__ target, const float* __restrict__ con,
    float* __restrict__ out)
{
    const int idx = blockIdx.x * 256 + threadIdx.x;  // 4-pixel group id
    const int w0  = (idx & 127) << 2;
    const int row = idx >> 7;                        // b*H + h
    const int h   = row & (HH - 1);
    const int b   = row >> 9;

    const int hm = (h > 0) ? h - 1 : 0;
    const int hp = (h < HH - 1) ? h + 1 : HH - 1;
    const float mh0 = (h > 0) ? 1.0f : 0.0f;
    const float mh1 = (h < HH - 1) ? 1.0f : 0.0f;
    v4 mwL = {(w0 == 0) ? 0.0f : 1.0f, 1.0f, 1.0f, 1.0f};
    v4 mwR = {1.0f, 1.0f, 1.0f, (w0 == WW - 4) ? 0.0f : 1.0f};

    const int offC = h * WW + w0;
    const int offU = hm * WW + w0;
    const int offD = hp * WW + w0;

    // con channels + per-pixel edge mask
    const float* cbase = con + b * CC * HWSZ;
    v4 conv4[8];
    v4 csum = {0.0f, 0.0f, 0.0f, 0.0f};
#pragma unroll
    for (int c = 0; c < 8; ++c) {
        conv4[c] = aload4(cbase + c * HWSZ + offC);
        csum += conv4[c];
    }
    v4 edge;
#pragma unroll
    for (int i = 0; i < 4; ++i)
        edge[i] = (csum[i] < 8.0f && csum[i] > 0.0f) ? 1.0f : 0.0f;

    const v4 t4 = aload4(target + b * HWSZ + offC);

    v4 glo1, vmin1, glo2, vmin2;
    float bi1, co1, bi2, co2;
    branch_eval(atts + b * CC * HWSZ, offC, offU, offD, mh0, mh1, mwL, mwR,
                conv4, glo1, vmin1, bi1, co1);
    branch_eval(dets + b * CC * HWSZ, offC, offU, offD, mh0, mh1, mwL, mwR,
                conv4, glo2, vmin2, bi2, co2);

    float pix = 0.0f;
#pragma unroll
    for (int i = 0; i < 4; ++i) {
        float dec = glo2[i] * (1.0f - edge[i]) + (1.0f - vmin2[i]) * edge[i];
        pix += bce2(glo1[i], t4[i]) + bce2(dec, t4[i]);
    }

    const float wbic = 0.2f / (float)(BB * CC * HWSZ);
    const float wcon = 0.8f / (float)(BB * CC * HWSZ);
    const float wpix = 1.0f / (float)(BB * HWSZ);
    const float ln2  = 0.69314718056f;

    float local = (wbic * (bi1 + bi2) + wcon * (co1 + co2) + wpix * pix) * ln2;

    // wave-64 reduce, then one atomic per block
#pragma unroll
    for (int off = 32; off > 0; off >>= 1)
        local += __shfl_down(local, off, 64);

    __shared__ float wsum[4];
    const int lane = threadIdx.x & 63;
    const int wid  = threadIdx.x >> 6;
    if (lane == 0) wsum[wid] = local;
    __syncthreads();
    if (threadIdx.x == 0) {
        float s = wsum[0] + wsum[1] + wsum[2] + wsum[3];
        atomicAdd(out, s);
    }
}

extern "C" void kernel_launch(void* const* d_in, const int* in_sizes, int n_in,
                              void* d_out, int out_size, void* d_ws, size_t ws_size,
                              hipStream_t stream) {
    const float* atts   = (const float*)d_in[0];
    const float* dets   = (const float*)d_in[1];
    const float* target = (const float*)d_in[2];
    const float* con    = (const float*)d_in[3];
    float* out = (float*)d_out;

    hipMemsetAsync(out, 0, sizeof(float), stream);

    const int ngroups = BB * HH * WW / 4;   // 524288 threads, 4 px each
    bicon_loss_kernel<<<ngroups / 256, 256, 0, stream>>>(atts, dets, target, con, out);
}

// Round 3
// 200.825 us; speedup vs baseline: 1.2675x; 1.0028x over previous
//
#include <hip/hip_runtime.h>

#define BB 8
#define CC 8
#define HH 512
#define WW 512
#define HWSZ (HH * WW)

typedef float v4 __attribute__((ext_vector_type(4)));

#define LOG2_CLAMP -144.26950409f   // -100 / ln2

__device__ __forceinline__ v4 uload4(const float* __restrict__ p) {
    v4 r;
    __builtin_memcpy(&r, p, sizeof(v4));   // 4B-aligned dwordx4
    return r;
}
__device__ __forceinline__ v4 aload4(const float* __restrict__ p) {
    return *(const v4* __restrict__)p;
}

__device__ __forceinline__ v4 sig4(v4 x) {
    v4 r;
#pragma unroll
    for (int i = 0; i < 4; ++i)
        r[i] = __builtin_amdgcn_rcpf(1.0f + __expf(-x[i]));
    return r;
}

// t>0.5 ? x : y, elementwise
__device__ __forceinline__ v4 vsel(v4 t, v4 x, v4 y) {
    v4 r;
#pragma unroll
    for (int i = 0; i < 4; ++i) r[i] = (t[i] > 0.5f) ? x[i] : y[i];
    return r;
}

// One branch (atts or dets): cr = raw center ch 0..7, nr = raw neighbor for vote k,
// cv = con channels, mk = per-vote masks. Accumulates POSITIVE log2 sums
// (bce = -ln2 * sum). bicon uses two 4-way products (votes can be 0), conn one 8-way.
template <bool NEED_MIN>
__device__ __forceinline__ void eval_branch(
    const v4* __restrict__ cr, const v4* __restrict__ nr,
    const v4* __restrict__ cv, const v4* __restrict__ mk,
    v4& glo, v4& vmin, float& Lbic, float& Lcon)
{
    v4 pb0 = {1.f, 1.f, 1.f, 1.f}, pb1 = {1.f, 1.f, 1.f, 1.f};
    v4 pc  = {1.f, 1.f, 1.f, 1.f};
    v4 vsum = {0.f, 0.f, 0.f, 0.f};
    if (NEED_MIN) vmin = {1e30f, 1e30f, 1e30f, 1e30f};
    v4 one = {1.f, 1.f, 1.f, 1.f};

#pragma unroll
    for (int k = 0; k < 8; ++k) {
        v4 s = sig4(cr[k]);
        v4 n = sig4(nr[k]) * mk[k];
        v4 v = s * n;
        vsum += v;
        if (NEED_MIN) vmin = __builtin_elementwise_min(vmin, v);
        v4 t  = cv[k];
        v4 av = vsel(t, v, one - v);
        v4 as = vsel(t, s, one - s);
        if (k < 4) pb0 *= av; else pb1 *= av;
        pc *= as;
    }
    glo = vsum * 0.125f;

    float lb = 0.f, lc = 0.f;
#pragma unroll
    for (int i = 0; i < 4; ++i) {
        lb += fmaxf(__log2f(pb0[i]), LOG2_CLAMP) + fmaxf(__log2f(pb1[i]), LOG2_CLAMP);
        lc += fmaxf(__log2f(pc[i]), LOG2_CLAMP);
    }
    Lbic = lb;
    Lcon = lc;
}

__global__ __launch_bounds__(256, 2) void bicon_loss_kernel(
    const float* __restrict__ atts, const float* __restrict__ dets,
    const float* __restrict__ target, const float* __restrict__ con,
    float* __restrict__ out)
{
    const int idx = blockIdx.x * 256 + threadIdx.x;  // 4-pixel group
    const int w0  = (idx & 127) << 2;
    const int row = idx >> 7;                        // b*H + h
    const int h   = row & (HH - 1);
    const int b   = row >> 9;

    const int hm = (h > 0) ? h - 1 : 0;
    const int hp = (h < HH - 1) ? h + 1 : HH - 1;
    const float mh0 = (h > 0) ? 1.0f : 0.0f;
    const float mh1 = (h < HH - 1) ? 1.0f : 0.0f;
    const v4 mwL = {(w0 == 0) ? 0.0f : 1.0f, 1.f, 1.f, 1.f};
    const v4 mwR = {1.f, 1.f, 1.f, (w0 == WW - 4) ? 0.0f : 1.0f};

    const int offC = h * WW + w0;
    const int offU = hm * WW + w0;
    const int offD = hp * WW + w0;

    const float* __restrict__ ab = atts + b * CC * HWSZ;
    const float* __restrict__ db = dets + b * CC * HWSZ;
    const float* __restrict__ cb = con  + b * CC * HWSZ;

    // ================= issue ALL 41 loads up front (max MLP) =================
    v4 ac[8], an[8], dc[8], dn[8], cv[8], t4;
#pragma unroll
    for (int c = 0; c < 8; ++c) ac[c] = aload4(ab + c * HWSZ + offC);
    an[0] = uload4(ab + 7 * HWSZ + offU - 1);
    an[1] = aload4(ab + 6 * HWSZ + offU);
    an[2] = uload4(ab + 5 * HWSZ + offU + 1);
    an[3] = uload4(ab + 4 * HWSZ + offC - 1);
    an[4] = uload4(ab + 3 * HWSZ + offC + 1);
    an[5] = uload4(ab + 2 * HWSZ + offD - 1);
    an[6] = aload4(ab + 1 * HWSZ + offD);
    an[7] = uload4(ab + 0 * HWSZ + offD + 1);
#pragma unroll
    for (int c = 0; c < 8; ++c) dc[c] = aload4(db + c * HWSZ + offC);
    dn[0] = uload4(db + 7 * HWSZ + offU - 1);
    dn[1] = aload4(db + 6 * HWSZ + offU);
    dn[2] = uload4(db + 5 * HWSZ + offU + 1);
    dn[3] = uload4(db + 4 * HWSZ + offC - 1);
    dn[4] = uload4(db + 3 * HWSZ + offC + 1);
    dn[5] = uload4(db + 2 * HWSZ + offD - 1);
    dn[6] = aload4(db + 1 * HWSZ + offD);
    dn[7] = uload4(db + 0 * HWSZ + offD + 1);
#pragma unroll
    for (int c = 0; c < 8; ++c) cv[c] = aload4(cb + c * HWSZ + offC);
    t4 = aload4(target + b * HWSZ + offC);
    // ========================================================================

    v4 mk[8];
    mk[0] = mwL * mh0;
    mk[1] = {mh0, mh0, mh0, mh0};
    mk[2] = mwR * mh0;
    mk[3] = mwL;
    mk[4] = mwR;
    mk[5] = mwL * mh1;
    mk[6] = {mh1, mh1, mh1, mh1};
    mk[7] = mwR * mh1;

    v4 csum = {0.f, 0.f, 0.f, 0.f};
#pragma unroll
    for (int c = 0; c < 8; ++c) csum += cv[c];
    v4 edge;
#pragma unroll
    for (int i = 0; i < 4; ++i)
        edge[i] = (csum[i] < 8.0f && csum[i] > 0.0f) ? 1.0f : 0.0f;

    v4 glo1, glo2, vmin1, vmin2;
    float Lb1, Lc1, Lb2, Lc2;
    eval_branch<false>(ac, an, cv, mk, glo1, vmin1, Lb1, Lc1);
    eval_branch<true >(dc, dn, cv, mk, glo2, vmin2, Lb2, Lc2);

    // pixel-level: bce(glo1,t) + bce(dec,t), combined into one log
    float Lp = 0.f;
#pragma unroll
    for (int i = 0; i < 4; ++i) {
        float dec = (edge[i] > 0.5f) ? (1.0f - vmin2[i]) : glo2[i];
        float a  = (t4[i] > 0.5f) ? glo1[i] : 1.0f - glo1[i];
        float bs = (t4[i] > 0.5f) ? dec     : 1.0f - dec;
        Lp += fmaxf(__log2f(a * bs), LOG2_CLAMP);
    }

    const float wbic = 0.2f / (float)(BB * CC * HWSZ);
    const float wcon = 0.8f / (float)(BB * CC * HWSZ);
    const float wpix = 1.0f / (float)(BB * HWSZ);
    const float ln2  = 0.69314718056f;

    float local = -(wbic * (Lb1 + Lb2) + wcon * (Lc1 + Lc2) + wpix * Lp) * ln2;

#pragma unroll
    for (int off = 32; off > 0; off >>= 1)
        local += __shfl_down(local, off, 64);

    __shared__ float wsum[4];
    const int lane = threadIdx.x & 63;
    const int wid  = threadIdx.x >> 6;
    if (lane == 0) wsum[wid] = local;
    __syncthreads();
    if (threadIdx.x == 0) {
        float s = wsum[0] + wsum[1] + wsum[2] + wsum[3];
        atomicAdd(out, s);
    }
}

extern "C" void kernel_launch(void* const* d_in, const int* in_sizes, int n_in,
                              void* d_out, int out_size, void* d_ws, size_t ws_size,
                              hipStream_t stream) {
    const float* atts   = (const float*)d_in[0];
    const float* dets   = (const float*)d_in[1];
    const float* target = (const float*)d_in[2];
    const float* con    = (const float*)d_in[3];
    float* out = (float*)d_out;

    hipMemsetAsync(out, 0, sizeof(float), stream);

    const int ngroups = BB * HH * WW / 4;   // 524288 threads, 4 px each
    bicon_loss_kernel<<<ngroups / 256, 256, 0, stream>>>(atts, dets, target, con, out);
}